// Round 15
// baseline (176.226 us; speedup 1.0000x reference)
//
#include <hip/hip_runtime.h>
#include <math.h>

typedef unsigned short u16;
typedef unsigned int u32;
typedef __attribute__((ext_vector_type(8))) short short8;
typedef __attribute__((ext_vector_type(4))) short short4v;
typedef __attribute__((ext_vector_type(4))) float f32x4;

#define BB 4
#define SS 2048
#define DD 1024
#define DV 64
#define NYU 1088  // col-dim of YU: 1024 Y + 64 U (pad cols dropped, R15)
#define BS (BB * SS)
#define SCALE (1.0f / 32.0f)
#define NTILE 136           // causal 128x128 tiles per batch
#define NSLOT (BB * NTILE)  // 544

__device__ __forceinline__ u16 f2bf(float f) {
    u32 u = __builtin_bit_cast(u32, f);
    u32 r = u + 0x7fffu + ((u >> 16) & 1u);  // RNE
    return (u16)(r >> 16);
}
__device__ __forceinline__ float bf2f(u16 b) {
    return __builtin_bit_cast(float, (u32)b << 16);
}

// prep_w: weights only. [0,768): cast+transpose Wq/Wk/Wv -> Wqt/Wkt/Wvt;
// [768,784): cast Wo -> Wo16.
__global__ __launch_bounds__(256) void prep_w(const float* __restrict__ Wq,
                                              const float* __restrict__ Wk,
                                              const float* __restrict__ Wv,
                                              const float* __restrict__ Wo,
                                              u16* __restrict__ Wqt,
                                              u16* __restrict__ Wkt,
                                              u16* __restrict__ Wvt,
                                              u16* __restrict__ Wo16) {
    __shared__ u16 t[64 * 72];  // 9 KB transpose staging
    const int b = blockIdx.x;
    const int tid = threadIdx.x;
    if (b < 768) {
        const int sel = b >> 8;
        const float* src = (sel == 0) ? Wq : (sel == 1) ? Wk : Wv;
        u16* dst = (sel == 0) ? Wqt : (sel == 1) ? Wkt : Wvt;
        const int rem = b & 255;
        const int e0 = (rem >> 4) * 64, d0 = (rem & 15) * 64;
        const int g = tid >> 6, lane = tid & 63;
        for (int r = g; r < 64; r += 4)
            t[r * 72 + lane] = f2bf(src[(size_t)(e0 + r) * DD + d0 + lane]);
        __syncthreads();
        for (int r = g; r < 64; r += 4)
            dst[(size_t)(d0 + r) * DD + e0 + lane] = t[lane * 72 + r];
    } else {
        // Wo [64][1024] f32 -> bf16: 16384 f32x4 over 16 blocks
#pragma unroll
        for (int j = 0; j < 4; ++j) {
            int i = (b - 768) * 1024 + j * 256 + tid;
            f32x4 v = ((const f32x4*)Wo)[i];
            short4v o;
            o.x = (short)f2bf(v.x); o.y = (short)f2bf(v.y);
            o.z = (short)f2bf(v.z); o.w = (short)f2bf(v.w);
            ((short4v*)Wo16)[i] = o;
        }
    }
}

// MERGED: Gt/Wvo split-K GEMM (blocks 0..1087) + x f32->bf16 cast (blocks
// 1088..9279). Fully independent segments — latency-bound GEMM blocks and
// BW-bound cast blocks interleave on the CUs; one launch boundary removed.
__global__ __launch_bounds__(256) void gtwvo_cast(const u16* __restrict__ Wkt,
                                                  const u16* __restrict__ Wqt,
                                                  const u16* __restrict__ Wo16,
                                                  const u16* __restrict__ Wvt,
                                                  const float* __restrict__ x,
                                                  u16* __restrict__ x16,
                                                  u16* __restrict__ GpartH,
                                                  u16* __restrict__ WvoPartH) {
    const int b = blockIdx.x;
    const int tid = threadIdx.x;
    if (b >= 1088) {  // ---- x cast segment ----
        int i = (b - 1088) * 256 + tid;
        f32x4 v = ((const f32x4*)x)[i];
        short4v o;
        o.x = (short)f2bf(v.x); o.y = (short)f2bf(v.y);
        o.z = (short)f2bf(v.z); o.w = (short)f2bf(v.w);
        ((short4v*)x16)[i] = o;
        return;
    }

    // ---- Gt / Wvo GEMM segment ----
    const u16 *A, *B;
    u16* C;
    int m0, n0;
    if (b < 1024) {
        const int z = b >> 8, t = b & 255;
        A = Wkt + z * 256;
        B = Wqt + z * 256;
        C = GpartH + (size_t)z * DD * DD;
        m0 = (t >> 4) * 64;
        n0 = (t & 15) * 64;
    } else {
        const int bb = b - 1024;
        const int kc = bb >> 4, t = bb & 15;
        A = Wo16 + kc * 256;
        B = Wvt + kc * 256;
        C = WvoPartH + (size_t)kc * DV * DD;
        m0 = 0;
        n0 = t * 64;
    }

    __shared__ u16 As[2][64 * 32];
    __shared__ u16 Bs[2][64 * 32];

    const int w = tid >> 6, lane = tid & 63;
    const int wm = w >> 1, wn = w & 1;
    const int lrow = lane >> 2;
    const int lcolsw = (((lane & 3) ^ ((lrow >> 1) & 3)) << 3);
    const int m16 = lane & 15;
    const int rdo = (((lane >> 4) ^ ((m16 >> 1) & 3)) << 3);

    f32x4 acc[2][2];
#pragma unroll
    for (int i = 0; i < 2; ++i)
#pragma unroll
        for (int j = 0; j < 2; ++j) acc[i][j] = (f32x4){0.f, 0.f, 0.f, 0.f};

    auto stage = [&](int t_, int bufi) {
        const int k0 = t_ * 32;
        {
            const u16* g = A + (size_t)(m0 + w * 16 + lrow) * DD + k0 + lcolsw;
            __builtin_amdgcn_global_load_lds(
                (const __attribute__((address_space(1))) void*)g,
                (__attribute__((address_space(3))) void*)(&As[bufi][w * 512]), 16, 0, 0);
        }
        {
            const u16* g = B + (size_t)(n0 + w * 16 + lrow) * DD + k0 + lcolsw;
            __builtin_amdgcn_global_load_lds(
                (const __attribute__((address_space(1))) void*)g,
                (__attribute__((address_space(3))) void*)(&Bs[bufi][w * 512]), 16, 0, 0);
        }
    };

    stage(0, 0);
    asm volatile("s_waitcnt vmcnt(0)" ::: "memory");
    __syncthreads();

    int cur = 0;
    for (int t_ = 0; t_ < 8; ++t_) {
        if (t_ + 1 < 8) stage(t_ + 1, cur ^ 1);

        short8 a[2], bb[2];
#pragma unroll
        for (int i = 0; i < 2; ++i)
            a[i] = *(const short8*)&As[cur][(wm * 32 + i * 16 + m16) * 32 + rdo];
#pragma unroll
        for (int j = 0; j < 2; ++j)
            bb[j] = *(const short8*)&Bs[cur][(wn * 32 + j * 16 + m16) * 32 + rdo];
#pragma unroll
        for (int i = 0; i < 2; ++i)
#pragma unroll
            for (int j = 0; j < 2; ++j)
                acc[i][j] = __builtin_amdgcn_mfma_f32_16x16x32_bf16(a[i], bb[j], acc[i][j], 0, 0, 0);

        if (t_ + 1 < 8) {
            asm volatile("s_waitcnt vmcnt(0)" ::: "memory");
            __syncthreads();
        }
        cur ^= 1;
    }

    const int crow0 = m0 + wm * 32 + (lane >> 4) * 4;
    const int ccol0 = n0 + wn * 32 + m16;
#pragma unroll
    for (int i = 0; i < 2; ++i)
#pragma unroll
        for (int j = 0; j < 2; ++j)
#pragma unroll
            for (int r = 0; r < 4; ++r)
                C[(size_t)(crow0 + i * 16 + r) * DD + ccol0 + j * 16] = f2bf(acc[i][j][r]);
}

// Wall2 rows 0..1023 = sum of 4 bf16 Gt partials; rows 1024..1087 = sum of
// 4 bf16 Wvo partials. Rows 1088..1151 stay garbage (staged by yu panel 8
// but their outputs are never written, NYU=1088).
__global__ __launch_bounds__(256) void reduce_all(const u16* __restrict__ GpartH,
                                                  const u16* __restrict__ WvoPartH,
                                                  u16* __restrict__ Wall2) {
    const int bx = blockIdx.x;
    const int e0 = threadIdx.x * 4;
    float s0 = 0.f, s1 = 0.f, s2 = 0.f, s3 = 0.f;
#pragma unroll
    for (int kc = 0; kc < 4; ++kc) {
        const u16* src = (bx < 1024)
                             ? &GpartH[(size_t)kc * DD * DD + (size_t)bx * DD + e0]
                             : &WvoPartH[(size_t)kc * DV * DD + (size_t)(bx - 1024) * DD + e0];
        short4v v = *(const short4v*)src;
        s0 += bf2f((u16)v.x); s1 += bf2f((u16)v.y);
        s2 += bf2f((u16)v.z); s3 += bf2f((u16)v.w);
    }
    short4v ov;
    ov.x = (short)f2bf(s0); ov.y = (short)f2bf(s1);
    ov.z = (short)f2bf(s2); ov.w = (short)f2bf(s3);
    *(short4v*)&Wall2[(size_t)bx * DD + e0] = ov;
}

// [Y|U] = x @ Wall2^T : M=8192, N logical 1088 (9 panels of 128; panel 8
// live cols 1024..1087 only). 576 blocks, XCD grid, 8 waves (512 thr),
// wave-tile 64x32, BK=32, 2-buf (R11 measured-best schedule).
// R15: YU row stride 1088 (pad cols dropped); panel-8 writes guarded.
__global__ __launch_bounds__(512) void yu_gemm(const u16* __restrict__ x16,
                                               const u16* __restrict__ Wall2,
                                               u16* __restrict__ YU,
                                               u16* __restrict__ Ut) {
    const int b = blockIdx.x;
    const int r = b & 7, q = b >> 3;
    const int m0 = (r * 8 + q / 9) * 128;
    const int n0 = (q % 9) * 128;

    __shared__ u16 As[2][128 * 32];
    __shared__ u16 Bs[2][128 * 32];

    const int tid = threadIdx.x;
    const int w = tid >> 6, lane = tid & 63;
    const int wm = w >> 2, wn = w & 3;  // wave tile 64(M) x 32(N)
    const int lrow = lane >> 2;
    const int lcolsw = (((lane & 3) ^ ((lrow >> 1) & 3)) << 3);
    const int m16 = lane & 15;
    const int rdo = (((lane >> 4) ^ ((m16 >> 1) & 3)) << 3);

    f32x4 acc[4][2];
#pragma unroll
    for (int i = 0; i < 4; ++i)
#pragma unroll
        for (int j = 0; j < 2; ++j) acc[i][j] = (f32x4){0.f, 0.f, 0.f, 0.f};

    auto stage = [&](int t, int bufi) {
        const int k0 = t * 32;
        {
            const u16* g = x16 + (size_t)(m0 + w * 16 + lrow) * DD + k0 + lcolsw;
            __builtin_amdgcn_global_load_lds(
                (const __attribute__((address_space(1))) void*)g,
                (__attribute__((address_space(3))) void*)(&As[bufi][w * 512]), 16, 0, 0);
        }
        {
            const u16* g = Wall2 + (size_t)(n0 + w * 16 + lrow) * DD + k0 + lcolsw;
            __builtin_amdgcn_global_load_lds(
                (const __attribute__((address_space(1))) void*)g,
                (__attribute__((address_space(3))) void*)(&Bs[bufi][w * 512]), 16, 0, 0);
        }
    };

    stage(0, 0);
    asm volatile("s_waitcnt vmcnt(0)" ::: "memory");
    __syncthreads();

    int cur = 0;
    for (int t = 0; t < 32; ++t) {
        if (t + 1 < 32) stage(t + 1, cur ^ 1);

        short8 a[4], bb[2];
#pragma unroll
        for (int i = 0; i < 4; ++i)
            a[i] = *(const short8*)&As[cur][(wm * 64 + i * 16 + m16) * 32 + rdo];
#pragma unroll
        for (int j = 0; j < 2; ++j)
            bb[j] = *(const short8*)&Bs[cur][(wn * 32 + j * 16 + m16) * 32 + rdo];
#pragma unroll
        for (int i = 0; i < 4; ++i)
#pragma unroll
            for (int j = 0; j < 2; ++j)
                acc[i][j] = __builtin_amdgcn_mfma_f32_16x16x32_bf16(a[i], bb[j], acc[i][j], 0, 0, 0);

        if (t + 1 < 32) {
            asm volatile("s_waitcnt vmcnt(0)" ::: "memory");
            __syncthreads();
        }
        cur ^= 1;
    }

    const int crow0 = m0 + wm * 64 + (lane >> 4) * 4;
    const int ccol0 = n0 + wn * 32 + m16;
#pragma unroll
    for (int i = 0; i < 4; ++i)
#pragma unroll
        for (int j = 0; j < 2; ++j)
#pragma unroll
            for (int r = 0; r < 4; ++r) {
                const float v = acc[i][j][r];
                const int cc = ccol0 + j * 16;
                if (cc < NYU)  // panel 8: cols >= 1088 are dead (NYU=1088)
                    YU[(size_t)(crow0 + i * 16 + r) * NYU + cc] = f2bf(v);
                if (n0 == 1024 && wn < 2)
                    Ut[(size_t)(cc - 1024) * BS + crow0 + i * 16 + r] = f2bf(v);
            }
}

// Fused causal scores + exp + PV. 128x128 tiles, 544 blocks, 8 waves (R11
// config, measured best). b&7 -> XCD, z=(b&7)>>1. Slot epilogue: Opart
// bf16, Lpart f32. Diagonal tiles skip wave-tiles above the causal boundary.
__global__ __launch_bounds__(512) void scores_pv(const u16* __restrict__ YU,
                                                 const u16* __restrict__ x16,
                                                 const u16* __restrict__ Ut,
                                                 u16* __restrict__ Opart,
                                                 float* __restrict__ Lpart) {
    const int b = blockIdx.x;
    const int r8 = b & 7;
    const int z = r8 >> 1;
    const int t = 2 * (b >> 3) + (r8 & 1);  // 0..135 within batch
    int y = (int)((sqrtf(8.f * t + 1.f) - 1.f) * 0.5f);
    while ((y + 1) * (y + 2) / 2 <= t) ++y;
    while (y * (y + 1) / 2 > t) --y;
    const int m0 = y * 128;
    const int n0 = (t - y * (y + 1) / 2) * 128;
    const int tglob = z * NTILE + t;

    const u16* A = YU + (size_t)z * SS * NYU;   // lda NYU (Y cols 0..1023)
    const u16* B = x16 + (size_t)z * SS * DD;   // ldb DD

    __shared__ union ShU {
        struct { u16 As[2][128 * 32]; u16 Bs[2][128 * 32]; } s;  // 32 KB
        u16 Ps[128 * 136];                                        // 34.8 KB
    } sh;

    const int tid = threadIdx.x;
    const int w = tid >> 6, lane = tid & 63;
    const int wm = w >> 2, wn = w & 3;  // wave tile 64(M) x 32(N)
    const int lrow = lane >> 2;
    const int lcolsw = (((lane & 3) ^ ((lrow >> 1) & 3)) << 3);
    const int m16 = lane & 15;
    const int kh = (lane >> 4) * 8;
    const int rdo = (((lane >> 4) ^ ((m16 >> 1) & 3)) << 3);

    // wave-tile fully above causal boundary? (diagonal tiles: wm=0,wn>=2)
    const bool live = (n0 + wn * 32) <= (m0 + wm * 64 + 63);

    f32x4 acc[4][2];
#pragma unroll
    for (int i = 0; i < 4; ++i)
#pragma unroll
        for (int j = 0; j < 2; ++j) acc[i][j] = (f32x4){0.f, 0.f, 0.f, 0.f};

    auto stage = [&](int tt, int bufi) {
        const int k0 = tt * 32;
        {
            const u16* g = A + (size_t)(m0 + w * 16 + lrow) * NYU + k0 + lcolsw;
            __builtin_amdgcn_global_load_lds(
                (const __attribute__((address_space(1))) void*)g,
                (__attribute__((address_space(3))) void*)(&sh.s.As[bufi][w * 512]), 16, 0, 0);
        }
        {
            const u16* g = B + (size_t)(n0 + w * 16 + lrow) * DD + k0 + lcolsw;
            __builtin_amdgcn_global_load_lds(
                (const __attribute__((address_space(1))) void*)g,
                (__attribute__((address_space(3))) void*)(&sh.s.Bs[bufi][w * 512]), 16, 0, 0);
        }
    };

    stage(0, 0);
    asm volatile("s_waitcnt vmcnt(0)" ::: "memory");
    __syncthreads();

    int cur = 0;
    for (int tt = 0; tt < 32; ++tt) {
        if (tt + 1 < 32) stage(tt + 1, cur ^ 1);

        if (live) {
            short8 a[4], bb[2];
#pragma unroll
            for (int i = 0; i < 4; ++i)
                a[i] = *(const short8*)&sh.s.As[cur][(wm * 64 + i * 16 + m16) * 32 + rdo];
#pragma unroll
            for (int j = 0; j < 2; ++j)
                bb[j] = *(const short8*)&sh.s.Bs[cur][(wn * 32 + j * 16 + m16) * 32 + rdo];
#pragma unroll
            for (int i = 0; i < 4; ++i)
#pragma unroll
                for (int j = 0; j < 2; ++j)
                    acc[i][j] = __builtin_amdgcn_mfma_f32_16x16x32_bf16(a[i], bb[j], acc[i][j], 0, 0, 0);
        }

        if (tt + 1 < 32) {
            asm volatile("s_waitcnt vmcnt(0)" ::: "memory");
            __syncthreads();
        }
        cur ^= 1;
    }
    __syncthreads();  // all waves done with As/Bs -> safe to reuse union as Ps

    // P' = exp(s*SCALE) (masked -> 0) into LDS [128][136]. No max subtraction:
    // s*SCALE ~ N(0,1), max ~5.5 sigma -> exp <= ~250, bf16/fp32 safe.
    const int rl0 = wm * 64 + (lane >> 4) * 4;
    const int cl0 = wn * 32 + m16;
#pragma unroll
    for (int i = 0; i < 4; ++i)
#pragma unroll
        for (int j = 0; j < 2; ++j)
#pragma unroll
            for (int r = 0; r < 4; ++r) {
                const int rl = rl0 + i * 16 + r;
                const int cl = cl0 + j * 16;
                float p = __expf(acc[i][j][r] * SCALE);
                sh.Ps[rl * 136 + cl] = (n0 + cl <= m0 + rl) ? f2bf(p) : (u16)0;
            }
    __syncthreads();

    // PV: wave w owns rows w*16..+15 of this tile; K = the tile's 128 cols.
    short8 ones8;
#pragma unroll
    for (int e = 0; e < 8; ++e) ones8[e] = (short)0x3F80;  // bf16 1.0

    const u16* Utz = Ut + (size_t)z * SS + n0;
    f32x4 accO[4], accL;
    accL = (f32x4){0.f, 0.f, 0.f, 0.f};
#pragma unroll
    for (int j = 0; j < 4; ++j) accO[j] = (f32x4){0.f, 0.f, 0.f, 0.f};
#pragma unroll
    for (int ks = 0; ks < 4; ++ks) {
        const int k0 = ks * 32;
        short8 a = *(const short8*)&sh.Ps[(w * 16 + m16) * 136 + k0 + kh];
        short8 bb[4];
#pragma unroll
        for (int j = 0; j < 4; ++j)
            bb[j] = *(const short8*)&Utz[(size_t)(j * 16 + m16) * BS + k0 + kh];
#pragma unroll
        for (int j = 0; j < 4; ++j)
            accO[j] = __builtin_amdgcn_mfma_f32_16x16x32_bf16(a, bb[j], accO[j], 0, 0, 0);
        accL = __builtin_amdgcn_mfma_f32_16x16x32_bf16(a, ones8, accL, 0, 0, 0);
    }

    // Stream to private slot (coalesced, write-once, no RMW). O as bf16.
    u16* Op = Opart + (size_t)tglob * (128 * 64);
    float* Lp = Lpart + (size_t)tglob * 128;
    const int lr0 = w * 16 + (lane >> 4) * 4;
#pragma unroll
    for (int j = 0; j < 4; ++j)
#pragma unroll
        for (int r = 0; r < 4; ++r)
            Op[(size_t)(lr0 + r) * DV + j * 16 + m16] = f2bf(accO[j][r]);
    if (m16 == 0)
#pragma unroll
        for (int r = 0; r < 4; ++r)
            Lp[lr0 + r] = accL[r];
}

// Gather slots + divide: out[row] = sum_c Opart[slot(row,c)] / sum_c Lpart.
__global__ __launch_bounds__(256) void normalize(float* __restrict__ out,
                                                 const u16* __restrict__ Opart,
                                                 const float* __restrict__ Lpart) {
    const int i = blockIdx.x * 256 + threadIdx.x;  // f32x4 index, 16 per row
    const int row = i >> 4;                        // 0..8191
    const int z = row >> 11, s = row & 2047;
    const int y = s >> 7, lr = s & 127;
    const int base = z * NTILE + y * (y + 1) / 2;
    const int nc = y + 1;
    const int col4 = (i & 15) * 4;

    f32x4 acc = (f32x4){0.f, 0.f, 0.f, 0.f};
    float L = 0.f;
    for (int c = 0; c < nc; ++c) {
        const int slot = base + c;
        short4v v = *(const short4v*)&Opart[(size_t)slot * (128 * 64) + (size_t)lr * 64 + col4];
        acc.x += bf2f((u16)v.x); acc.y += bf2f((u16)v.y);
        acc.z += bf2f((u16)v.z); acc.w += bf2f((u16)v.w);
        L += Lpart[(size_t)slot * 128 + lr];
    }
    const float inv = 1.f / L;
    acc.x *= inv; acc.y *= inv; acc.z *= inv; acc.w *= inv;
    ((f32x4*)out)[i] = acc;
}

extern "C" void kernel_launch(void* const* d_in, const int* in_sizes, int n_in,
                              void* d_out, int out_size, void* d_ws, size_t ws_size,
                              hipStream_t stream) {
    const float* x  = (const float*)d_in[0];
    const float* Wq = (const float*)d_in[1];
    const float* Wk = (const float*)d_in[2];
    const float* Wv = (const float*)d_in[3];
    const float* Wo = (const float*)d_in[4];
    float* out = (float*)d_out;

    // ws layout (~54 MB)
    u16* x16   = (u16*)d_ws;                           // [8192,1024]  16.8 MB
    u16* Wqt   = x16 + (size_t)BB * SS * DD;           // [1024,1024]   2.1
    u16* Wkt   = Wqt + (size_t)DD * DD;                // [1024,1024]   2.1
    u16* Wvt   = Wkt + (size_t)DD * DD;                // [1024,1024]   2.1
    u16* Wo16  = Wvt + (size_t)DD * DD;                // [64,1024]     0.13
    u16* Wall2 = Wo16 + (size_t)DV * DD;               // [1152,1024]   2.36
    u16* YU    = Wall2 + (size_t)1152 * DD;            // [8192,1088]  17.8
    u16* Ut    = YU + (size_t)BB * SS * NYU;           // [64,8192]     1.05
    u16* Opart = Ut + (size_t)DV * BS;                 // [544,128,64] bf16 8.9
    float* Lpart = (float*)(Opart + (size_t)NSLOT * 128 * DV);  // [544,128] 0.28
    // aliases into YU region (dead until yu_gemm runs):
    u16* GpartH   = YU;                                // [4,1024,1024] bf16 8.4
    u16* WvoPartH = GpartH + (size_t)4 * DD * DD;      // [4,64,1024]  bf16 0.5

    prep_w<<<dim3(784), 256, 0, stream>>>(Wq, Wk, Wv, Wo, Wqt, Wkt, Wvt, Wo16);

    // Gt split-K=4 (1024 blocks) + Wvo split-K=4 (64 blocks) + x cast (8192
    // blocks) merged: independent segments overlap on the CUs.
    gtwvo_cast<<<dim3(9280), 256, 0, stream>>>(Wkt, Wqt, Wo16, Wvt, x, x16,
                                               GpartH, WvoPartH);

    reduce_all<<<dim3(1088), 256, 0, stream>>>(GpartH, WvoPartH, Wall2);

    yu_gemm<<<dim3(576), 512, 0, stream>>>(x16, Wall2, YU, Ut);

    scores_pv<<<dim3(544), 512, 0, stream>>>(YU, x16, Ut, Opart, Lpart);

    normalize<<<dim3(out_size / 4 / 256), 256, 0, stream>>>(out, Opart, Lpart);
}

// Round 16
// 174.591 us; speedup vs baseline: 1.0094x; 1.0094x over previous
//
#include <hip/hip_runtime.h>
#include <math.h>

typedef unsigned short u16;
typedef unsigned int u32;
typedef __attribute__((ext_vector_type(8))) short short8;
typedef __attribute__((ext_vector_type(4))) short short4v;
typedef __attribute__((ext_vector_type(4))) float f32x4;

#define BB 4
#define SS 2048
#define DD 1024
#define DV 64
#define NYU 1152  // col-dim of YU: 1024 Y + 64 U + 64 pad
#define BS (BB * SS)
#define SCALE (1.0f / 32.0f)
#define NTILE 136           // causal 128x128 tiles per batch
#define NSLOT (BB * NTILE)  // 544

__device__ __forceinline__ u16 f2bf(float f) {
    u32 u = __builtin_bit_cast(u32, f);
    u32 r = u + 0x7fffu + ((u >> 16) & 1u);  // RNE
    return (u16)(r >> 16);
}
__device__ __forceinline__ float bf2f(u16 b) {
    return __builtin_bit_cast(float, (u32)b << 16);
}

// prep_w: weights only. [0,768): cast+transpose Wq/Wk/Wv -> Wqt/Wkt/Wvt;
// [768,784): cast Wo -> Wo16.
__global__ __launch_bounds__(256) void prep_w(const float* __restrict__ Wq,
                                              const float* __restrict__ Wk,
                                              const float* __restrict__ Wv,
                                              const float* __restrict__ Wo,
                                              u16* __restrict__ Wqt,
                                              u16* __restrict__ Wkt,
                                              u16* __restrict__ Wvt,
                                              u16* __restrict__ Wo16) {
    __shared__ u16 t[64 * 72];  // 9 KB transpose staging
    const int b = blockIdx.x;
    const int tid = threadIdx.x;
    if (b < 768) {
        const int sel = b >> 8;
        const float* src = (sel == 0) ? Wq : (sel == 1) ? Wk : Wv;
        u16* dst = (sel == 0) ? Wqt : (sel == 1) ? Wkt : Wvt;
        const int rem = b & 255;
        const int e0 = (rem >> 4) * 64, d0 = (rem & 15) * 64;
        const int g = tid >> 6, lane = tid & 63;
        for (int r = g; r < 64; r += 4)
            t[r * 72 + lane] = f2bf(src[(size_t)(e0 + r) * DD + d0 + lane]);
        __syncthreads();
        for (int r = g; r < 64; r += 4)
            dst[(size_t)(d0 + r) * DD + e0 + lane] = t[lane * 72 + r];
    } else {
        // Wo [64][1024] f32 -> bf16: 16384 f32x4 over 16 blocks
#pragma unroll
        for (int j = 0; j < 4; ++j) {
            int i = (b - 768) * 1024 + j * 256 + tid;
            f32x4 v = ((const f32x4*)Wo)[i];
            short4v o;
            o.x = (short)f2bf(v.x); o.y = (short)f2bf(v.y);
            o.z = (short)f2bf(v.z); o.w = (short)f2bf(v.w);
            ((short4v*)Wo16)[i] = o;
        }
    }
}

// MERGED: Gt/Wvo split-K GEMM (blocks 0..1087) + x f32->bf16 cast (blocks
// 1088..9279). Fully independent segments — latency-bound GEMM blocks and
// BW-bound cast blocks interleave on the CUs; one launch boundary removed.
__global__ __launch_bounds__(256) void gtwvo_cast(const u16* __restrict__ Wkt,
                                                  const u16* __restrict__ Wqt,
                                                  const u16* __restrict__ Wo16,
                                                  const u16* __restrict__ Wvt,
                                                  const float* __restrict__ x,
                                                  u16* __restrict__ x16,
                                                  u16* __restrict__ GpartH,
                                                  u16* __restrict__ WvoPartH) {
    const int b = blockIdx.x;
    const int tid = threadIdx.x;
    if (b >= 1088) {  // ---- x cast segment ----
        int i = (b - 1088) * 256 + tid;
        f32x4 v = ((const f32x4*)x)[i];
        short4v o;
        o.x = (short)f2bf(v.x); o.y = (short)f2bf(v.y);
        o.z = (short)f2bf(v.z); o.w = (short)f2bf(v.w);
        ((short4v*)x16)[i] = o;
        return;
    }

    // ---- Gt / Wvo GEMM segment ----
    const u16 *A, *B;
    u16* C;
    int m0, n0;
    if (b < 1024) {
        const int z = b >> 8, t = b & 255;
        A = Wkt + z * 256;
        B = Wqt + z * 256;
        C = GpartH + (size_t)z * DD * DD;
        m0 = (t >> 4) * 64;
        n0 = (t & 15) * 64;
    } else {
        const int bb = b - 1024;
        const int kc = bb >> 4, t = bb & 15;
        A = Wo16 + kc * 256;
        B = Wvt + kc * 256;
        C = WvoPartH + (size_t)kc * DV * DD;
        m0 = 0;
        n0 = t * 64;
    }

    __shared__ u16 As[2][64 * 32];
    __shared__ u16 Bs[2][64 * 32];

    const int w = tid >> 6, lane = tid & 63;
    const int wm = w >> 1, wn = w & 1;
    const int lrow = lane >> 2;
    const int lcolsw = (((lane & 3) ^ ((lrow >> 1) & 3)) << 3);
    const int m16 = lane & 15;
    const int rdo = (((lane >> 4) ^ ((m16 >> 1) & 3)) << 3);

    f32x4 acc[2][2];
#pragma unroll
    for (int i = 0; i < 2; ++i)
#pragma unroll
        for (int j = 0; j < 2; ++j) acc[i][j] = (f32x4){0.f, 0.f, 0.f, 0.f};

    auto stage = [&](int t_, int bufi) {
        const int k0 = t_ * 32;
        {
            const u16* g = A + (size_t)(m0 + w * 16 + lrow) * DD + k0 + lcolsw;
            __builtin_amdgcn_global_load_lds(
                (const __attribute__((address_space(1))) void*)g,
                (__attribute__((address_space(3))) void*)(&As[bufi][w * 512]), 16, 0, 0);
        }
        {
            const u16* g = B + (size_t)(n0 + w * 16 + lrow) * DD + k0 + lcolsw;
            __builtin_amdgcn_global_load_lds(
                (const __attribute__((address_space(1))) void*)g,
                (__attribute__((address_space(3))) void*)(&Bs[bufi][w * 512]), 16, 0, 0);
        }
    };

    stage(0, 0);
    asm volatile("s_waitcnt vmcnt(0)" ::: "memory");
    __syncthreads();

    int cur = 0;
    for (int t_ = 0; t_ < 8; ++t_) {
        if (t_ + 1 < 8) stage(t_ + 1, cur ^ 1);

        short8 a[2], bb[2];
#pragma unroll
        for (int i = 0; i < 2; ++i)
            a[i] = *(const short8*)&As[cur][(wm * 32 + i * 16 + m16) * 32 + rdo];
#pragma unroll
        for (int j = 0; j < 2; ++j)
            bb[j] = *(const short8*)&Bs[cur][(wn * 32 + j * 16 + m16) * 32 + rdo];
#pragma unroll
        for (int i = 0; i < 2; ++i)
#pragma unroll
            for (int j = 0; j < 2; ++j)
                acc[i][j] = __builtin_amdgcn_mfma_f32_16x16x32_bf16(a[i], bb[j], acc[i][j], 0, 0, 0);

        if (t_ + 1 < 8) {
            asm volatile("s_waitcnt vmcnt(0)" ::: "memory");
            __syncthreads();
        }
        cur ^= 1;
    }

    const int crow0 = m0 + wm * 32 + (lane >> 4) * 4;
    const int ccol0 = n0 + wn * 32 + m16;
#pragma unroll
    for (int i = 0; i < 2; ++i)
#pragma unroll
        for (int j = 0; j < 2; ++j)
#pragma unroll
            for (int r = 0; r < 4; ++r)
                C[(size_t)(crow0 + i * 16 + r) * DD + ccol0 + j * 16] = f2bf(acc[i][j][r]);
}

// Wall2 rows 0..1023 = sum of 4 bf16 Gt partials; rows 1024..1087 = sum of
// 4 bf16 Wvo partials. (rows 1088..1151 garbage — never read.)
__global__ __launch_bounds__(256) void reduce_all(const u16* __restrict__ GpartH,
                                                  const u16* __restrict__ WvoPartH,
                                                  u16* __restrict__ Wall2) {
    const int bx = blockIdx.x;
    const int e0 = threadIdx.x * 4;
    float s0 = 0.f, s1 = 0.f, s2 = 0.f, s3 = 0.f;
#pragma unroll
    for (int kc = 0; kc < 4; ++kc) {
        const u16* src = (bx < 1024)
                             ? &GpartH[(size_t)kc * DD * DD + (size_t)bx * DD + e0]
                             : &WvoPartH[(size_t)kc * DV * DD + (size_t)(bx - 1024) * DD + e0];
        short4v v = *(const short4v*)src;
        s0 += bf2f((u16)v.x); s1 += bf2f((u16)v.y);
        s2 += bf2f((u16)v.z); s3 += bf2f((u16)v.w);
    }
    short4v ov;
    ov.x = (short)f2bf(s0); ov.y = (short)f2bf(s1);
    ov.z = (short)f2bf(s2); ov.w = (short)f2bf(s3);
    *(short4v*)&Wall2[(size_t)bx * DD + e0] = ov;
}

// [Y|U] = x @ Wall2^T : M=8192, N=1152, 128x128 tiles, 576 blocks, XCD grid.
// R11 config (measured best): 8 waves (512 thr), wave-tile 64x32, BK=32,
// 2-buf, 1-ahead stage, vmcnt(0)+barrier. Panel n0==1024, wn<2 -> Ut.
__global__ __launch_bounds__(512) void yu_gemm(const u16* __restrict__ x16,
                                               const u16* __restrict__ Wall2,
                                               u16* __restrict__ YU,
                                               u16* __restrict__ Ut) {
    const int b = blockIdx.x;
    const int r = b & 7, q = b >> 3;
    const int m0 = (r * 8 + q / 9) * 128;
    const int n0 = (q % 9) * 128;

    __shared__ u16 As[2][128 * 32];
    __shared__ u16 Bs[2][128 * 32];

    const int tid = threadIdx.x;
    const int w = tid >> 6, lane = tid & 63;
    const int wm = w >> 2, wn = w & 3;  // wave tile 64(M) x 32(N)
    const int lrow = lane >> 2;
    const int lcolsw = (((lane & 3) ^ ((lrow >> 1) & 3)) << 3);
    const int m16 = lane & 15;
    const int rdo = (((lane >> 4) ^ ((m16 >> 1) & 3)) << 3);

    f32x4 acc[4][2];
#pragma unroll
    for (int i = 0; i < 4; ++i)
#pragma unroll
        for (int j = 0; j < 2; ++j) acc[i][j] = (f32x4){0.f, 0.f, 0.f, 0.f};

    auto stage = [&](int t, int bufi) {
        const int k0 = t * 32;
        {
            const u16* g = x16 + (size_t)(m0 + w * 16 + lrow) * DD + k0 + lcolsw;
            __builtin_amdgcn_global_load_lds(
                (const __attribute__((address_space(1))) void*)g,
                (__attribute__((address_space(3))) void*)(&As[bufi][w * 512]), 16, 0, 0);
        }
        {
            const u16* g = Wall2 + (size_t)(n0 + w * 16 + lrow) * DD + k0 + lcolsw;
            __builtin_amdgcn_global_load_lds(
                (const __attribute__((address_space(1))) void*)g,
                (__attribute__((address_space(3))) void*)(&Bs[bufi][w * 512]), 16, 0, 0);
        }
    };

    stage(0, 0);
    asm volatile("s_waitcnt vmcnt(0)" ::: "memory");
    __syncthreads();

    int cur = 0;
    for (int t = 0; t < 32; ++t) {
        if (t + 1 < 32) stage(t + 1, cur ^ 1);

        short8 a[4], bb[2];
#pragma unroll
        for (int i = 0; i < 4; ++i)
            a[i] = *(const short8*)&As[cur][(wm * 64 + i * 16 + m16) * 32 + rdo];
#pragma unroll
        for (int j = 0; j < 2; ++j)
            bb[j] = *(const short8*)&Bs[cur][(wn * 32 + j * 16 + m16) * 32 + rdo];
#pragma unroll
        for (int i = 0; i < 4; ++i)
#pragma unroll
            for (int j = 0; j < 2; ++j)
                acc[i][j] = __builtin_amdgcn_mfma_f32_16x16x32_bf16(a[i], bb[j], acc[i][j], 0, 0, 0);

        if (t + 1 < 32) {
            asm volatile("s_waitcnt vmcnt(0)" ::: "memory");
            __syncthreads();
        }
        cur ^= 1;
    }

    const int crow0 = m0 + wm * 64 + (lane >> 4) * 4;
    const int ccol0 = n0 + wn * 32 + m16;
#pragma unroll
    for (int i = 0; i < 4; ++i)
#pragma unroll
        for (int j = 0; j < 2; ++j)
#pragma unroll
            for (int r = 0; r < 4; ++r) {
                const float v = acc[i][j][r];
                YU[(size_t)(crow0 + i * 16 + r) * NYU + ccol0 + j * 16] = f2bf(v);
                if (n0 == 1024 && wn < 2)
                    Ut[(size_t)(ccol0 + j * 16 - 1024) * BS + crow0 + i * 16 + r] = f2bf(v);
            }
}

// Fused causal scores + exp + PV. 128x128 tiles, 544 blocks, 8 waves (R11
// config, measured best). b&7 -> XCD, z=(b&7)>>1. Slot epilogue: Opart
// bf16, Lpart f32. Diagonal tiles skip the wave-tiles entirely above the
// causal boundary (wave-uniform guard; exp-phase mask writes zeros there).
__global__ __launch_bounds__(512) void scores_pv(const u16* __restrict__ YU,
                                                 const u16* __restrict__ x16,
                                                 const u16* __restrict__ Ut,
                                                 u16* __restrict__ Opart,
                                                 float* __restrict__ Lpart) {
    const int b = blockIdx.x;
    const int r8 = b & 7;
    const int z = r8 >> 1;
    const int t = 2 * (b >> 3) + (r8 & 1);  // 0..135 within batch
    int y = (int)((sqrtf(8.f * t + 1.f) - 1.f) * 0.5f);
    while ((y + 1) * (y + 2) / 2 <= t) ++y;
    while (y * (y + 1) / 2 > t) --y;
    const int m0 = y * 128;
    const int n0 = (t - y * (y + 1) / 2) * 128;
    const int tglob = z * NTILE + t;

    const u16* A = YU + (size_t)z * SS * NYU;   // lda NYU (Y cols 0..1023)
    const u16* B = x16 + (size_t)z * SS * DD;   // ldb DD

    __shared__ union ShU {
        struct { u16 As[2][128 * 32]; u16 Bs[2][128 * 32]; } s;  // 32 KB
        u16 Ps[128 * 136];                                        // 34.8 KB
    } sh;

    const int tid = threadIdx.x;
    const int w = tid >> 6, lane = tid & 63;
    const int wm = w >> 2, wn = w & 3;  // wave tile 64(M) x 32(N)
    const int lrow = lane >> 2;
    const int lcolsw = (((lane & 3) ^ ((lrow >> 1) & 3)) << 3);
    const int m16 = lane & 15;
    const int kh = (lane >> 4) * 8;
    const int rdo = (((lane >> 4) ^ ((m16 >> 1) & 3)) << 3);

    // wave-tile fully above causal boundary? (diagonal tiles: wm=0,wn>=2)
    const bool live = (n0 + wn * 32) <= (m0 + wm * 64 + 63);

    f32x4 acc[4][2];
#pragma unroll
    for (int i = 0; i < 4; ++i)
#pragma unroll
        for (int j = 0; j < 2; ++j) acc[i][j] = (f32x4){0.f, 0.f, 0.f, 0.f};

    auto stage = [&](int tt, int bufi) {
        const int k0 = tt * 32;
        {
            const u16* g = A + (size_t)(m0 + w * 16 + lrow) * NYU + k0 + lcolsw;
            __builtin_amdgcn_global_load_lds(
                (const __attribute__((address_space(1))) void*)g,
                (__attribute__((address_space(3))) void*)(&sh.s.As[bufi][w * 512]), 16, 0, 0);
        }
        {
            const u16* g = B + (size_t)(n0 + w * 16 + lrow) * DD + k0 + lcolsw;
            __builtin_amdgcn_global_load_lds(
                (const __attribute__((address_space(1))) void*)g,
                (__attribute__((address_space(3))) void*)(&sh.s.Bs[bufi][w * 512]), 16, 0, 0);
        }
    };

    stage(0, 0);
    asm volatile("s_waitcnt vmcnt(0)" ::: "memory");
    __syncthreads();

    int cur = 0;
    for (int tt = 0; tt < 32; ++tt) {
        if (tt + 1 < 32) stage(tt + 1, cur ^ 1);

        if (live) {
            short8 a[4], bb[2];
#pragma unroll
            for (int i = 0; i < 4; ++i)
                a[i] = *(const short8*)&sh.s.As[cur][(wm * 64 + i * 16 + m16) * 32 + rdo];
#pragma unroll
            for (int j = 0; j < 2; ++j)
                bb[j] = *(const short8*)&sh.s.Bs[cur][(wn * 32 + j * 16 + m16) * 32 + rdo];
#pragma unroll
            for (int i = 0; i < 4; ++i)
#pragma unroll
                for (int j = 0; j < 2; ++j)
                    acc[i][j] = __builtin_amdgcn_mfma_f32_16x16x32_bf16(a[i], bb[j], acc[i][j], 0, 0, 0);
        }

        if (tt + 1 < 32) {
            asm volatile("s_waitcnt vmcnt(0)" ::: "memory");
            __syncthreads();
        }
        cur ^= 1;
    }
    __syncthreads();  // all waves done with As/Bs -> safe to reuse union as Ps

    // P' = exp(s*SCALE) (masked -> 0) into LDS [128][136]. No max subtraction:
    // s*SCALE ~ N(0,1), max ~5.5 sigma -> exp <= ~250, bf16/fp32 safe.
    const int rl0 = wm * 64 + (lane >> 4) * 4;
    const int cl0 = wn * 32 + m16;
#pragma unroll
    for (int i = 0; i < 4; ++i)
#pragma unroll
        for (int j = 0; j < 2; ++j)
#pragma unroll
            for (int r = 0; r < 4; ++r) {
                const int rl = rl0 + i * 16 + r;
                const int cl = cl0 + j * 16;
                float p = __expf(acc[i][j][r] * SCALE);
                sh.Ps[rl * 136 + cl] = (n0 + cl <= m0 + rl) ? f2bf(p) : (u16)0;
            }
    __syncthreads();

    // PV: wave w owns rows w*16..+15 of this tile; K = the tile's 128 cols.
    short8 ones8;
#pragma unroll
    for (int e = 0; e < 8; ++e) ones8[e] = (short)0x3F80;  // bf16 1.0

    const u16* Utz = Ut + (size_t)z * SS + n0;
    f32x4 accO[4], accL;
    accL = (f32x4){0.f, 0.f, 0.f, 0.f};
#pragma unroll
    for (int j = 0; j < 4; ++j) accO[j] = (f32x4){0.f, 0.f, 0.f, 0.f};
#pragma unroll
    for (int ks = 0; ks < 4; ++ks) {
        const int k0 = ks * 32;
        short8 a = *(const short8*)&sh.Ps[(w * 16 + m16) * 136 + k0 + kh];
        short8 bb[4];
#pragma unroll
        for (int j = 0; j < 4; ++j)
            bb[j] = *(const short8*)&Utz[(size_t)(j * 16 + m16) * BS + k0 + kh];
#pragma unroll
        for (int j = 0; j < 4; ++j)
            accO[j] = __builtin_amdgcn_mfma_f32_16x16x32_bf16(a, bb[j], accO[j], 0, 0, 0);
        accL = __builtin_amdgcn_mfma_f32_16x16x32_bf16(a, ones8, accL, 0, 0, 0);
    }

    // Stream to private slot (coalesced, write-once, no RMW). O as bf16.
    u16* Op = Opart + (size_t)tglob * (128 * 64);
    float* Lp = Lpart + (size_t)tglob * 128;
    const int lr0 = w * 16 + (lane >> 4) * 4;
#pragma unroll
    for (int j = 0; j < 4; ++j)
#pragma unroll
        for (int r = 0; r < 4; ++r)
            Op[(size_t)(lr0 + r) * DV + j * 16 + m16] = f2bf(accO[j][r]);
    if (m16 == 0)
#pragma unroll
        for (int r = 0; r < 4; ++r)
            Lp[lr0 + r] = accL[r];
}

// Gather slots + divide: out[row] = sum_c Opart[slot(row,c)] / sum_c Lpart.
__global__ __launch_bounds__(256) void normalize(float* __restrict__ out,
                                                 const u16* __restrict__ Opart,
                                                 const float* __restrict__ Lpart) {
    const int i = blockIdx.x * 256 + threadIdx.x;  // f32x4 index, 16 per row
    const int row = i >> 4;                        // 0..8191
    const int z = row >> 11, s = row & 2047;
    const int y = s >> 7, lr = s & 127;
    const int base = z * NTILE + y * (y + 1) / 2;
    const int nc = y + 1;
    const int col4 = (i & 15) * 4;

    f32x4 acc = (f32x4){0.f, 0.f, 0.f, 0.f};
    float L = 0.f;
    for (int c = 0; c < nc; ++c) {
        const int slot = base + c;
        short4v v = *(const short4v*)&Opart[(size_t)slot * (128 * 64) + (size_t)lr * 64 + col4];
        acc.x += bf2f((u16)v.x); acc.y += bf2f((u16)v.y);
        acc.z += bf2f((u16)v.z); acc.w += bf2f((u16)v.w);
        L += Lpart[(size_t)slot * 128 + lr];
    }
    const float inv = 1.f / L;
    acc.x *= inv; acc.y *= inv; acc.z *= inv; acc.w *= inv;
    ((f32x4*)out)[i] = acc;
}

extern "C" void kernel_launch(void* const* d_in, const int* in_sizes, int n_in,
                              void* d_out, int out_size, void* d_ws, size_t ws_size,
                              hipStream_t stream) {
    const float* x  = (const float*)d_in[0];
    const float* Wq = (const float*)d_in[1];
    const float* Wk = (const float*)d_in[2];
    const float* Wv = (const float*)d_in[3];
    const float* Wo = (const float*)d_in[4];
    float* out = (float*)d_out;

    // ws layout (~55 MB)
    u16* x16   = (u16*)d_ws;                           // [8192,1024]  16.8 MB
    u16* Wqt   = x16 + (size_t)BB * SS * DD;           // [1024,1024]   2.1
    u16* Wkt   = Wqt + (size_t)DD * DD;                // [1024,1024]   2.1
    u16* Wvt   = Wkt + (size_t)DD * DD;                // [1024,1024]   2.1
    u16* Wo16  = Wvt + (size_t)DD * DD;                // [64,1024]     0.13
    u16* Wall2 = Wo16 + (size_t)DV * DD;               // [1152,1024]   2.36
    u16* YU    = Wall2 + (size_t)NYU * DD;             // [8192,1152]  18.9
    u16* Ut    = YU + (size_t)BB * SS * NYU;           // [64,8192]     1.05
    u16* Opart = Ut + (size_t)DV * BS;                 // [544,128,64] bf16 8.9
    float* Lpart = (float*)(Opart + (size_t)NSLOT * 128 * DV);  // [544,128] 0.28
    // aliases into YU region (dead until yu_gemm runs):
    u16* GpartH   = YU;                                // [4,1024,1024] bf16 8.4
    u16* WvoPartH = GpartH + (size_t)4 * DD * DD;      // [4,64,1024]  bf16 0.5

    prep_w<<<dim3(784), 256, 0, stream>>>(Wq, Wk, Wv, Wo, Wqt, Wkt, Wvt, Wo16);

    // Gt split-K=4 (1024 blocks) + Wvo split-K=4 (64 blocks) + x cast (8192
    // blocks) merged: independent segments overlap on the CUs.
    gtwvo_cast<<<dim3(9280), 256, 0, stream>>>(Wkt, Wqt, Wo16, Wvt, x, x16,
                                               GpartH, WvoPartH);

    reduce_all<<<dim3(1088), 256, 0, stream>>>(GpartH, WvoPartH, Wall2);

    yu_gemm<<<dim3(576), 512, 0, stream>>>(x16, Wall2, YU, Ut);

    scores_pv<<<dim3(544), 512, 0, stream>>>(YU, x16, Ut, Opart, Lpart);

    normalize<<<dim3(out_size / 4 / 256), 256, 0, stream>>>(out, Opart, Lpart);
}